// Round 9
// baseline (3219.232 us; speedup 1.0000x reference)
//
#include <hip/hip_runtime.h>
#include <hip/hip_bf16.h>

typedef _Float16 f16x2 __attribute__((ext_vector_type(2)));

#define HID 300
#define NSEQ 64
#define NROWS 4096   // B*N = 64*64

union U { uint4 u; f16x2 h[4]; };

__device__ __forceinline__ float sigm(float x){ return 1.f/(1.f+__expf(-x)); }

__device__ __forceinline__ float fdot2a(f16x2 a, f16x2 b, float c){
#if __has_builtin(__builtin_amdgcn_fdot2)
  return __builtin_amdgcn_fdot2(a, b, c, false);
#else
  return c + (float)a.x*(float)b.x + (float)a.y*(float)b.y;
#endif
}

// Relaxed agent-scope ops: LLC-coherent, NO cache maintenance (no L2 flush).
__device__ __forceinline__ void xstore(float* p, float v){
  __hip_atomic_store(p, v, __ATOMIC_RELAXED, __HIP_MEMORY_SCOPE_AGENT);
}
__device__ __forceinline__ float xload(const float* p){
  return __hip_atomic_load(p, __ATOMIC_RELAXED, __HIP_MEMORY_SCOPE_AGENT);
}

// ---------------------------------------------------------------------------
// Merged repack: f32 -> fp16 pairs, [kg][outs][4 pairs] coalesced; also zeroes
// the pipeline sync counters + claim pools every launch.
// ---------------------------------------------------------------------------
__global__ void convert_all_kernel(
    const float* __restrict__ whh_c, const float* __restrict__ wih_p,
    const float* __restrict__ wih_c, const float* __restrict__ whh_p,
    const float* __restrict__ wr0,   const float* __restrict__ wr1,
    const float* __restrict__ w_in,  const float* __restrict__ w1,
    const float* __restrict__ w2,
    f16x2* __restrict__ W_M4, f16x2* __restrict__ WrT4, f16x2* __restrict__ W_P4,
    f16x2* __restrict__ W_H4, f16x2* __restrict__ W_14, f16x2* __restrict__ W_24,
    int* __restrict__ syncc)
{
  const int NA = 4*38*1800*4;
  const int NB = 4*38*600*4;
  const int NP = 4*38*1800*4;
  const int NH = 128*300*4;
  const int N1 = 318*304*4;
  const int N2 = 38*304*4;
  const int NS = 3*64*16 + 64;   // step counters + claim pools
  const int TOT = NA+NB+NP+NH+N1+N2+NS;
  for (int idx0 = blockIdx.x*blockDim.x + threadIdx.x; idx0 < TOT; idx0 += gridDim.x*blockDim.x){
    int idx = idx0;
    if (idx < NA){
      int l    = idx/(38*1800*4);
      int rem  = idx - l*(38*1800*4);
      int kg   = rem/(1800*4);
      int rem2 = rem - kg*(1800*4);
      int o = rem2>>2, s = rem2&3;
      int c = (kg*4+s)*2;
      float v0=0.f, v1=0.f;
      if (c < 300){
        const float* src = (o<900) ? (whh_c + ((size_t)l*900+o)*300)
                                   : (wih_p + ((size_t)l*900+(o-900))*300);
        v0 = src[c]; v1 = src[c+1];
      }
      f16x2 t; t.x=(_Float16)v0; t.y=(_Float16)v1;
      W_M4[idx] = t; continue;
    }
    idx -= NA;
    if (idx < NB){
      int l    = idx/(38*600*4);
      int rem  = idx - l*(38*600*4);
      int kg   = rem/(600*4);
      int rem2 = rem - kg*(600*4);
      int t6 = rem2>>2, s = rem2&3;
      int d = t6>>1, hh = t6&1;
      int c = (kg*4+s)*2;
      float v0=0.f, v1=0.f;
      if (c < 300){
        const float* src = hh ? (wr1 + ((size_t)l*300+d)*300)
                              : (wr0 + ((size_t)l*300+d)*300);
        v0 = src[c]; v1 = src[c+1];
      }
      f16x2 t; t.x=(_Float16)v0; t.y=(_Float16)v1;
      WrT4[idx] = t; continue;
    }
    idx -= NB;
    if (idx < NP){
      int l    = idx/(38*1800*4);
      int rem  = idx - l*(38*1800*4);
      int kg   = rem/(1800*4);
      int rem2 = rem - kg*(1800*4);
      int o = rem2>>2, s = rem2&3;
      int c = (kg*4+s)*2;
      float v0=0.f, v1=0.f;
      if (c < 300){
        const float* src = (o<900) ? (wih_c + ((size_t)l*900+o)*300)
                                   : (whh_p + ((size_t)l*900+(o-900))*300);
        v0 = src[c]; v1 = src[c+1];
      }
      f16x2 t; t.x=(_Float16)v0; t.y=(_Float16)v1;
      W_P4[idx] = t; continue;
    }
    idx -= NP;
    if (idx < NH){
      int kg  = idx/(300*4);
      int rem = idx - kg*(300*4);
      int o = rem>>2, s = rem&3;
      int c = (kg*4+s)*2;
      f16x2 t; t.x=(_Float16)w_in[(size_t)o*1024+c]; t.y=(_Float16)w_in[(size_t)o*1024+c+1];
      W_H4[idx] = t; continue;
    }
    idx -= NH;
    if (idx < N1){
      int kgg = idx/(304*4);
      int rem = idx - kgg*(304*4);
      int o = rem>>2, s = rem&3;
      int segbase, seglen, kgl;
      if (kgg < 190){ int seg = kgg/38; kgl = kgg - seg*38; segbase = seg*300; seglen = 300; }
      else { int kk = kgg-190; int sf = kk>>6; kgl = kk&63; segbase = 1500 + sf*512; seglen = 512; }
      int c = (kgl*4+s)*2;
      float v0=0.f, v1=0.f;
      if (o < 300 && c < seglen){
        v0 = w1[(size_t)o*2524 + segbase + c];
        if (c+1 < seglen) v1 = w1[(size_t)o*2524 + segbase + c + 1];
      }
      f16x2 t; t.x=(_Float16)v0; t.y=(_Float16)v1;
      W_14[idx] = t; continue;
    }
    idx -= N1;
    if (idx < N2){
      int kg = idx/(304*4);
      int rem = idx - kg*(304*4);
      int o = rem>>2, s = rem&3;
      int c = (kg*4+s)*2;
      float v0=0.f, v1=0.f;
      if (o < 300 && c < 300){ v0 = w2[(size_t)o*300+c]; v1 = w2[(size_t)o*300+c+1]; }
      f16x2 t; t.x=(_Float16)v0; t.y=(_Float16)v1;
      W_24[idx] = t; continue;
    }
    idx -= N2;
    syncc[idx] = 0;
  }
}

// ---------------------------------------------------------------------------
// H0 = relu(features @ w_in^T + b_in), coalesced fp16 weights.
// ---------------------------------------------------------------------------
__global__ __launch_bounds__(256) void h0_kernel(const float* __restrict__ feat,
    const f16x2* __restrict__ WH, const float* __restrict__ b_in, float* __restrict__ H0)
{
  const int tid = threadIdx.x;
  const int r0  = blockIdx.x*8;
  __shared__ f16x2 X[8][512];
  for (int t=tid; t<8*512; t+=256){
    int r=t>>9, p=t&511, c=2*p;
    f16x2 h; h.x=(_Float16)feat[(size_t)(r0+r)*1024+c];
    h.y=(_Float16)feat[(size_t)(r0+r)*1024+c+1];
    X[r][p]=h;
  }
  __syncthreads();
  const uint4* WHu = (const uint4*)WH;
  const int o0 = tid, o1 = tid+256;
  const bool h1v = (o1 < 300);
  float acc[2][8];
  #pragma unroll
  for (int j=0;j<2;j++)
    #pragma unroll
    for (int r=0;r<8;r++) acc[j][r]=0.f;
  for (int kg=0; kg<128; kg++){
    U w0, w1;
    w0.u = WHu[(size_t)kg*300 + o0];
    if (h1v) w1.u = WHu[(size_t)kg*300 + o1];
    #pragma unroll
    for (int r=0;r<8;r++){
      const f16x2* xp = &X[r][kg*4];
      f16x2 x0=xp[0],x1=xp[1],x2=xp[2],x3=xp[3];
      acc[0][r] = fdot2a(w0.h[3],x3, fdot2a(w0.h[2],x2, fdot2a(w0.h[1],x1, fdot2a(w0.h[0],x0, acc[0][r]))));
      if (h1v)
        acc[1][r] = fdot2a(w1.h[3],x3, fdot2a(w1.h[2],x2, fdot2a(w1.h[1],x1, fdot2a(w1.h[0],x0, acc[1][r]))));
    }
  }
  {
    float bb = b_in[o0];
    #pragma unroll
    for (int r=0;r<8;r++) H0[(size_t)(r0+r)*HID + o0] = fmaxf(acc[0][r]+bb, 0.f);
  }
  if (h1v){
    float bb = b_in[o1];
    #pragma unroll
    for (int r=0;r<8;r++) H0[(size_t)(r0+r)*HID + o1] = fmaxf(acc[1][r]+bb, 0.f);
  }
}

// ---------------------------------------------------------------------------
// Fused 4-layer pipelined scan, XCD-aware claimed placement.
// 256 WGs; each claims a (layer, chain): preferred layer = XCC_ID>>1.
// DYNAMIC LDS pad (launch config: 25600 B) raises total LDS to ~86.5 KB so
// exactly 1 WG/CU fits -> 256 WGs on 256 CUs, 32/XCD, claim pools fill with
// zero spill -> each XCD's L2 holds ONE layer's 2.55 MB weight set.
// (R8 bug: static pad array was dead-store-eliminated; dynamic LDS cannot be.)
// ---------------------------------------------------------------------------
__global__ __launch_bounds__(1024) void scan_pipe_kernel(
  float* __restrict__ Hball,
  const f16x2* __restrict__ W_M4, const f16x2* __restrict__ WrT4, const f16x2* __restrict__ W_P4,
  const float* __restrict__ bih_c, const float* __restrict__ bhh_c,
  const float* __restrict__ bih_p, const float* __restrict__ bhh_p,
  const float* __restrict__ gwq, const float* __restrict__ gwk, const float* __restrict__ gbv,
  const int* __restrict__ speakers, float* __restrict__ xrow, int* __restrict__ syncc)
{
  __shared__ _Float16 Hh[NSEQ][304];
  __shared__ float pre_s[1800];
  __shared__ float gates[1800];
  __shared__ float Mf[304];
  __shared__ f16x2 Mh[152];
  __shared__ f16x2 u01h[304];
  __shared__ float wgt[NSEQ];
  __shared__ float kd[NSEQ];
  __shared__ float red[320];
  __shared__ float xf[304];
  __shared__ f16x2 xh[152];
  __shared__ int   spk[NSEQ];
  __shared__ int   startA[NSEQ];
  __shared__ int   sLayer, sChain;
  extern __shared__ float dynpad[];   // 25600 B from launch config — occupancy limiter

  const int tid = threadIdx.x;

  // --- claim (layer, chain) with XCD-local preference ---
  if (tid == 0){
    int xcc = 0;
    asm volatile("s_getreg_b32 %0, hwreg(HW_REG_XCC_ID)" : "=s"(xcc));
    int pref = (xcc >> 1) & 3;
    int* claimc = syncc + 3*64*16;
    int l = 0, c = 0;
    #pragma unroll 1
    for (int t=0; t<4; ++t){
      int cand = (pref + t) & 3;
      int idx = __hip_atomic_fetch_add(&claimc[cand*16], 1, __ATOMIC_RELAXED, __HIP_MEMORY_SCOPE_AGENT);
      if (idx < 64){ l = cand; c = idx; break; }
    }
    sLayer = l; sChain = c;
    if (xcc == 0x7FFFFFFF){ volatile float* vp = dynpad; vp[0] = 1.f; }  // keep dynpad referenced
  }
  __syncthreads();
  const int layer = sLayer;
  const int chain = sChain;
  const int base  = chain * NSEQ;

  const uint4* Wm4 = (const uint4*)(W_M4 + (size_t)layer*38*1800*4);
  const uint4* Wr4 = (const uint4*)(WrT4 + (size_t)layer*38*600*4);
  const uint4* Wp4 = (const uint4*)(W_P4 + (size_t)layer*38*1800*4);
  const float* HinB = Hball + (size_t)base*300;                       // layer 0 input
  float* HoutB = Hball + ((size_t)(layer+1)*NROWS + (size_t)base)*300;
  const float gb = gbv[layer];
  int* cntP = syncc + (layer*64 + chain)*16;
  int* cntC = (layer>0) ? (syncc + ((layer-1)*64 + chain)*16) : (int*)0;
  const float* xin  = xrow + (size_t)((layer-1)*64 + chain)*NSEQ*300; // layer>0
  float*       xout = xrow + (size_t)(layer*64 + chain)*NSEQ*300;     // layer<3

  // step-invariant per-thread regs
  float bcr=0,bcz=0,bcn=0,bpr=0,bpz=0,bpn=0,wkv=0;
  if (tid < 300){
    bcr=bhh_c[layer*900+tid]; bcz=bhh_c[layer*900+300+tid]; bcn=bhh_c[layer*900+600+tid];
    bpr=bih_p[layer*900+tid]; bpz=bih_p[layer*900+300+tid]; bpn=bih_p[layer*900+600+tid];
    wkv=gwk[layer*300+tid];
  }
  float wq0r=0, wq1r=0;
  if (tid < 150){ wq0r = gwq[layer*300+2*tid]; wq1r = gwq[layer*300+2*tid+1]; }
  const int pt  = tid - 64;        // pre-GEMV thread index (waves 1..15)
  const int po1 = pt, po2 = 960 + pt;
  const bool p2v = (pt >= 0) && (pt < 840);
  float pb1=0, pb2=0;
  if (tid >= 64){
    pb1 = (po1<900) ? bih_c[layer*900+po1] : bhh_p[layer*900+po1-900];
    if (p2v) pb2 = bhh_p[layer*900+po2-900];
  }
  const int o1 = tid, o2 = tid+1024;
  const bool dhas2 = (o2 < 1800);

  if (tid < NSEQ) spk[tid] = speakers[base+tid];
  if (tid >= 300 && tid < 320) red[tid]=0.f;
  if (tid >= 300 && tid < 304) xf[tid]=0.f;
  for (int t=tid; t<1800; t+=1024) gates[t]=0.f;
  if (tid < 304) Mf[tid]=0.f;
  if (tid < 2){
    f16x2 z; z.x=(_Float16)0.f; z.y=(_Float16)0.f;
    Mh[150+tid]=z; xh[150+tid]=z; u01h[150+tid]=z; u01h[302+tid]=z;
  }
  __syncthreads();
  if (tid < NSEQ){
    int s=0; for (int j=tid-1;j>=0;--j) if (spk[j]==spk[tid]){s=j;break;}
    startA[tid]=s;
  }
  if (layer>0 && tid==0){
    while (__hip_atomic_load(cntC, __ATOMIC_RELAXED, __HIP_MEMORY_SCOPE_AGENT) < 1)
      __builtin_amdgcn_s_sleep(8);
  }
  __syncthreads();

  for (int i=0; i<NSEQ; ++i){
    // R: receive/load input row i -> xf (f32) + xh (fp16) + qd partial products
    if (tid < 150){
      float x0, x1;
      if (layer==0){
        float2 v = *(const float2*)(HinB + (size_t)i*300 + 2*tid);
        x0=v.x; x1=v.y;
      } else {
        x0 = xload(xin + (size_t)i*300 + 2*tid);
        x1 = xload(xin + (size_t)i*300 + 2*tid + 1);
      }
      xf[2*tid]=x0; xf[2*tid+1]=x1;
      f16x2 h; h.x=(_Float16)x0; h.y=(_Float16)x1; xh[tid]=h;
      red[tid] = x0*wq0r + x1*wq1r;
    }
    __syncthreads();
    // P: fused pre-GEMV on waves 1..15  ||  A: qd-reduce + softmax on wave 0
    if (tid >= 64){
      float a0=0,a1=0,a2=0,a3=0, e0=0,e1=0,e2=0,e3=0;
      for (int kg=0;kg<38;kg++){
        U v0, v1;
        v0.u = Wp4[(size_t)kg*1800 + po1];
        if (p2v) v1.u = Wp4[(size_t)kg*1800 + po2];
        f16x2 x0=xh[kg*4+0],x1=xh[kg*4+1],x2=xh[kg*4+2],x3=xh[kg*4+3];
        a0=fdot2a(v0.h[0],x0,a0); a1=fdot2a(v0.h[1],x1,a1);
        a2=fdot2a(v0.h[2],x2,a2); a3=fdot2a(v0.h[3],x3,a3);
        if (p2v){ e0=fdot2a(v1.h[0],x0,e0); e1=fdot2a(v1.h[1],x1,e1);
                  e2=fdot2a(v1.h[2],x2,e2); e3=fdot2a(v1.h[3],x3,e3); }
      }
      pre_s[po1] = (a0+a1)+(a2+a3) + pb1;
      if (p2v) pre_s[po2] = (e0+e1)+(e2+e3) + pb2;
    } else if (i > 0){
      float s = red[tid] + red[tid+64] + ((tid<22)? red[tid+128] : 0.f);
      #pragma unroll
      for (int o=32;o>0;o>>=1) s += __shfl_xor(s,o);
      const float q = s;
      const int st = startA[i];
      const bool in = (tid>=st) && (tid<i);
      float a = in ? (q + kd[tid] + gb) : -3.0e38f;
      float m = a;
      #pragma unroll
      for (int o=32;o>0;o>>=1) m = fmaxf(m,__shfl_xor(m,o));
      float e = in ? __expf(a-m) : 0.f;
      float ss = e;
      #pragma unroll
      for (int o=32;o>0;o>>=1) ss += __shfl_xor(ss,o);
      wgt[tid] = e/ss;
    }
    __syncthreads();
    if (i > 0){
      // B: u0 (same-speaker) / u1 (other) weighted history sums
      if (tid < 600){
        const int d  = (tid<300)? tid : (tid-300);
        const int wh = (tid>=300);
        const int st = startA[i]; const int ms = spk[i];
        float u=0.f;
        for (int j=st;j<i;++j){
          float sel = ((spk[j]==ms) != (wh!=0)) ? 1.f : 0.f;
          u += sel*wgt[j]*(float)Hh[j][d];
        }
        ((_Float16*)u01h)[(wh?304:0) + d] = (_Float16)u;
      }
      __syncthreads();
      // C: M = wr0@u0 + wr1@u1 ; pair-combine + Mh pack via in-wave shuffles
      if (tid < 600){
        const int hh = tid&1;
        const f16x2* uu = (const f16x2*)u01h + hh*152;
        float a0=0,a1=0,a2=0,a3=0;
        for (int kg=0;kg<38;kg++){
          U v; v.u = Wr4[(size_t)kg*600 + tid];
          a0=fdot2a(v.h[0],uu[kg*4+0],a0);
          a1=fdot2a(v.h[1],uu[kg*4+1],a1);
          a2=fdot2a(v.h[2],uu[kg*4+2],a2);
          a3=fdot2a(v.h[3],uu[kg*4+3],a3);
        }
        float a = (a0+a1)+(a2+a3);
        float m2 = a + __shfl_xor(a,1);         // M[d], d = tid>>1
        if ((tid&1)==0) Mf[tid>>1] = m2;
        float mo = __shfl_xor(m2,2);            // M[d^1]
        if ((tid&3)==0){ f16x2 mh; mh.x=(_Float16)m2; mh.y=(_Float16)mo; Mh[tid>>2]=mh; }
      }
      __syncthreads();
      // D: gates = [whh_c ; wih_p] @ M (1800 rows, 2/thread)
      {
        float a0=0,a1=0,a2=0,a3=0, e0=0,e1=0,e2=0,e3=0;
        for (int kg=0;kg<38;kg++){
          U v0, v1;
          v0.u = Wm4[(size_t)kg*1800 + o1];
          if (dhas2) v1.u = Wm4[(size_t)kg*1800 + o2];
          f16x2 m0=Mh[kg*4+0], m1=Mh[kg*4+1], m2=Mh[kg*4+2], m3=Mh[kg*4+3];
          a0=fdot2a(v0.h[0],m0,a0); a1=fdot2a(v0.h[1],m1,a1);
          a2=fdot2a(v0.h[2],m2,a2); a3=fdot2a(v0.h[3],m3,a3);
          if (dhas2){ e0=fdot2a(v1.h[0],m0,e0); e1=fdot2a(v1.h[1],m1,e1);
                      e2=fdot2a(v1.h[2],m2,e2); e3=fdot2a(v1.h[3],m3,e3); }
        }
        gates[o1] = (a0+a1)+(a2+a3);
        if (dhas2) gates[o2] = (e0+e1)+(e2+e3);
      }
      __syncthreads();
    }
    // E: GRU combine; write Hout + own history + publish to consumer
    if (tid < 300){
      const float M = Mf[tid];
      float r  = sigm(pre_s[tid] + gates[tid] + bcr);
      float z  = sigm(pre_s[300+tid] + gates[300+tid] + bcz);
      float n  = tanhf(pre_s[600+tid] + r*(gates[600+tid]+bcn));
      float C  = (1.f-z)*n + z*M;
      float rp = sigm(gates[900+tid]+bpr + pre_s[900+tid]);
      float zp = sigm(gates[1200+tid]+bpz + pre_s[1200+tid]);
      float np = tanhf(gates[1500+tid]+bpn + rp*pre_s[1500+tid]);
      float qv = xf[tid];
      float P  = (1.f-zp)*np + zp*qv;
      float h  = C + P;
      HoutB[(size_t)i*300 + tid] = h;
      Hh[i][tid] = (_Float16)h;
      red[tid] = h*wkv;
      if (layer<3) xstore(xout + (size_t)i*300 + tid, h);
    }
    asm volatile("s_waitcnt vmcnt(0)" ::: "memory");   // drain publish before counting
    __syncthreads();
    // F: kd[i]; bump own counter; poll producer for next row
    if (tid < 64){
      float s = red[tid]+red[tid+64]+red[tid+128]+red[tid+192]+red[tid+256];
      #pragma unroll
      for (int o=32;o>0;o>>=1) s += __shfl_xor(s,o);
      if (tid==0) kd[i]=s;
    }
    if (tid==0){
      if (layer<3) __hip_atomic_fetch_add(cntP, 1, __ATOMIC_RELAXED, __HIP_MEMORY_SCOPE_AGENT);
      if (layer>0 && i<63){
        while (__hip_atomic_load(cntC, __ATOMIC_RELAXED, __HIP_MEMORY_SCOPE_AGENT) < i+2)
          __builtin_amdgcn_s_sleep(8);
      }
    }
    __syncthreads();
  }
}

// ---------------------------------------------------------------------------
// Head with fp16-dot2 GEMMs (unchanged).
// ---------------------------------------------------------------------------
__global__ __launch_bounds__(256) void head_kernel(
  const float* __restrict__ H0, const float* __restrict__ Hl1,
  const float* __restrict__ Hl2, const float* __restrict__ Hl3,
  const float* __restrict__ Hl4, const float* __restrict__ feat,
  const f16x2* __restrict__ W14, const float* __restrict__ b1,
  const f16x2* __restrict__ W24, const float* __restrict__ b2,
  const float* __restrict__ w3, const float* __restrict__ b3,
  float* __restrict__ out)
{
  const int tid = threadIdx.x;
  const int r0  = blockIdx.x*16;
  __shared__ f16x2 Xh[16*256];
  __shared__ _Float16 h1h[16*304];
  __shared__ float S2[16*304];
  const uint4* W14u = (const uint4*)W14;
  const uint4* W24u = (const uint4*)W24;

  float acc0[16], acc1[16];
  #pragma unroll
  for (int r=0;r<16;r++){ acc0[r]=0.f; acc1[r]=0.f; }
  const int o  = tid;
  const int o2 = tid + 256;
  const bool has2 = (o2 < 300);

  #pragma unroll
  for (int seg=0; seg<7; seg++){
    const float* src = (seg==0)?H0:(seg==1)?Hl1:(seg==2)?Hl2:(seg==3)?Hl3:(seg==4)?Hl4:feat;
    if (seg < 5){
      for (int t=tid; t<16*152; t+=256){
        int r=t/152, p=t-r*152, c=2*p;
        float v0 = (c<300)? src[(size_t)(r0+r)*300 + c] : 0.f;
        float v1 = (c+1<300)? src[(size_t)(r0+r)*300 + c+1] : 0.f;
        f16x2 h; h.x=(_Float16)v0; h.y=(_Float16)v1;
        Xh[r*256+p] = h;
      }
    } else {
      const int cb = (seg-5)*512;
      for (int t=tid; t<16*256; t+=256){
        int r=t>>8, p=t&255;
        float v0 = src[(size_t)(r0+r)*1024 + cb + 2*p];
        float v1 = src[(size_t)(r0+r)*1024 + cb + 2*p+1];
        f16x2 h; h.x=(_Float16)v0; h.y=(_Float16)v1;
        Xh[r*256+p] = h;
      }
    }
    __syncthreads();
    const int kgs = (seg<5)?38:64;
    const int kgo = (seg<5)? seg*38 : 190+(seg-5)*64;
    if (o < 300){
      for (int kg=0; kg<kgs; kg++){
        U a, b;
        a.u = W14u[(size_t)(kgo+kg)*304 + o];
        if (has2) b.u = W14u[(size_t)(kgo+kg)*304 + o2];
        #pragma unroll
        for (int r=0;r<16;r++){
          const f16x2* xp = &Xh[r*256 + kg*4];
          float t0 = fdot2a(a.h[0], xp[0], 0.f);
          t0 = fdot2a(a.h[1], xp[1], t0);
          t0 = fdot2a(a.h[2], xp[2], t0);
          t0 = fdot2a(a.h[3], xp[3], t0);
          acc0[r] += t0;
          if (has2){
            float t1 = fdot2a(b.h[0], xp[0], 0.f);
            t1 = fdot2a(b.h[1], xp[1], t1);
            t1 = fdot2a(b.h[2], xp[2], t1);
            t1 = fdot2a(b.h[3], xp[3], t1);
            acc1[r] += t1;
          }
        }
      }
    }
    __syncthreads();
  }
  if (o < 300){
    float bb = b1[o];
    #pragma unroll
    for (int r=0;r<16;r++) h1h[r*304+o] = (_Float16)fmaxf(acc0[r]+bb, 0.f);
  }
  if (has2){
    float bb = b1[o2];
    #pragma unroll
    for (int r=0;r<16;r++) h1h[r*304+o2] = (_Float16)fmaxf(acc1[r]+bb, 0.f);
  }
  if (tid < 4){
    #pragma unroll
    for (int r=0;r<16;r++) h1h[r*304+300+tid] = (_Float16)0.f;
  }
  __syncthreads();
  #pragma unroll
  for (int r=0;r<16;r++){ acc0[r]=0.f; acc1[r]=0.f; }
  if (o < 300){
    for (int kg=0; kg<38; kg++){
      U a, b;
      a.u = W24u[(size_t)kg*304 + o];
      if (has2) b.u = W24u[(size_t)kg*304 + o2];
      #pragma unroll
      for (int r=0;r<16;r++){
        const f16x2* xp = (const f16x2*)&h1h[r*304] + kg*4;
        float t0 = fdot2a(a.h[0], xp[0], 0.f);
        t0 = fdot2a(a.h[1], xp[1], t0);
        t0 = fdot2a(a.h[2], xp[2], t0);
        t0 = fdot2a(a.h[3], xp[3], t0);
        acc0[r] += t0;
        if (has2){
          float t1 = fdot2a(b.h[0], xp[0], 0.f);
          t1 = fdot2a(b.h[1], xp[1], t1);
          t1 = fdot2a(b.h[2], xp[2], t1);
          t1 = fdot2a(b.h[3], xp[3], t1);
          acc1[r] += t1;
        }
      }
    }
  }
  __syncthreads();
  if (o < 300){
    float bb = b2[o];
    #pragma unroll
    for (int r=0;r<16;r++) S2[r*304+o] = fmaxf(acc0[r]+bb, 0.f);
  }
  if (has2){
    float bb = b2[o2];
    #pragma unroll
    for (int r=0;r<16;r++) S2[r*304+o2] = fmaxf(acc1[r]+bb, 0.f);
  }
  __syncthreads();
  if (tid < 16*7){
    int r = tid/7, c = tid - r*7;
    float s = b3[c];
    const float* wrow = w3 + (size_t)c*HID;
    for (int k=0;k<HID;k++) s += wrow[k]*S2[r*304+k];
    out[(size_t)(r0+r)*7 + c] = s;
  }
}

// ---------------------------------------------------------------------------
extern "C" void kernel_launch(void* const* d_in, const int* in_sizes, int n_in,
                              void* d_out, int out_size, void* d_ws, size_t ws_size,
                              hipStream_t stream)
{
  (void)in_sizes; (void)n_in; (void)out_size; (void)ws_size;
  const float* feat  = (const float*)d_in[0];
  const int*   spk   = (const int*)d_in[1];
  const float* w_in  = (const float*)d_in[2];
  const float* b_in  = (const float*)d_in[3];
  const float* gwq   = (const float*)d_in[4];
  const float* gwk   = (const float*)d_in[5];
  const float* gb    = (const float*)d_in[6];
  const float* wr0   = (const float*)d_in[7];
  const float* wr1   = (const float*)d_in[8];
  const float* wih_c = (const float*)d_in[9];
  const float* whh_c = (const float*)d_in[10];
  const float* bih_c = (const float*)d_in[11];
  const float* bhh_c = (const float*)d_in[12];
  const float* wih_p = (const float*)d_in[13];
  const float* whh_p = (const float*)d_in[14];
  const float* bih_p = (const float*)d_in[15];
  const float* bhh_p = (const float*)d_in[16];
  const float* w1    = (const float*)d_in[17];
  const float* b1    = (const float*)d_in[18];
  const float* w2    = (const float*)d_in[19];
  const float* b2    = (const float*)d_in[20];
  const float* w3    = (const float*)d_in[21];
  const float* b3    = (const float*)d_in[22];
  float* out = (float*)d_out;

  char* ws = (char*)d_ws;
  size_t off = 0;
  auto alloc = [&](size_t bytes)->void*{
    void* p = ws + off;
    off += (bytes + 255) & ~(size_t)255;
    return p;
  };
  f16x2* W_M4 = (f16x2*)alloc((size_t)4*38*1800*4 * sizeof(f16x2));
  f16x2* WrT4 = (f16x2*)alloc((size_t)4*38*600*4  * sizeof(f16x2));
  f16x2* W_P4 = (f16x2*)alloc((size_t)4*38*1800*4 * sizeof(f16x2));
  f16x2* W_H4 = (f16x2*)alloc((size_t)128*300*4   * sizeof(f16x2));
  f16x2* W_14 = (f16x2*)alloc((size_t)318*304*4   * sizeof(f16x2));
  f16x2* W_24 = (f16x2*)alloc((size_t)38*304*4    * sizeof(f16x2));
  float* Hball = (float*)alloc((size_t)5*NROWS*HID*sizeof(float));
  float* xrow  = (float*)alloc((size_t)3*64*NSEQ*HID*sizeof(float));
  int*   syncc = (int*)alloc((size_t)(3*64*16 + 64)*sizeof(int));

  {
    const int tot = 4*38*1800*4 + 4*38*600*4 + 4*38*1800*4 + 128*300*4
                  + 318*304*4 + 38*304*4 + (3*64*16 + 64);
    convert_all_kernel<<<(tot+255)/256, 256, 0, stream>>>(whh_c, wih_p, wih_c, whh_p,
        wr0, wr1, w_in, w1, w2, W_M4, WrT4, W_P4, W_H4, W_14, W_24, syncc);
  }
  h0_kernel<<<NROWS/8, 256, 0, stream>>>(feat, W_H4, b_in, Hball);

  // 25600 B dynamic LDS: total ~86.5 KB/WG -> exactly 1 WG/CU (occupancy limiter)
  scan_pipe_kernel<<<256, 1024, 25600, stream>>>(Hball, W_M4, WrT4, W_P4,
      bih_c, bhh_c, bih_p, bhh_p, gwq, gwk, gb, spk, xrow, syncc);

  head_kernel<<<NROWS/16, 256, 0, stream>>>(
      Hball, Hball + (size_t)NROWS*HID, Hball + (size_t)2*NROWS*HID,
      Hball + (size_t)3*NROWS*HID, Hball + (size_t)4*NROWS*HID,
      feat, W_14, b1, W_24, b2, w3, b3, out);
}

// Round 10
// 2328.733 us; speedup vs baseline: 1.3824x; 1.3824x over previous
//
#include <hip/hip_runtime.h>
#include <hip/hip_bf16.h>

typedef _Float16 f16x2 __attribute__((ext_vector_type(2)));

#define HID 300
#define NSEQ 64
#define NROWS 4096   // B*N = 64*64

union U { uint4 u; f16x2 h[4]; };

__device__ __forceinline__ float sigm(float x){ return 1.f/(1.f+__expf(-x)); }

__device__ __forceinline__ float fdot2a(f16x2 a, f16x2 b, float c){
#if __has_builtin(__builtin_amdgcn_fdot2)
  return __builtin_amdgcn_fdot2(a, b, c, false);
#else
  return c + (float)a.x*(float)b.x + (float)a.y*(float)b.y;
#endif
}

// Relaxed agent-scope ops: LLC-coherent, NO cache maintenance (no L2 flush).
__device__ __forceinline__ void xstore(float* p, float v){
  __hip_atomic_store(p, v, __ATOMIC_RELAXED, __HIP_MEMORY_SCOPE_AGENT);
}
__device__ __forceinline__ float xload(const float* p){
  return __hip_atomic_load(p, __ATOMIC_RELAXED, __HIP_MEMORY_SCOPE_AGENT);
}

// ---------------------------------------------------------------------------
// Merged repack: f32 -> fp16 pairs, [kg][outs][4 pairs] coalesced; also zeroes
// the pipeline sync counters + claim pools every launch.
// ---------------------------------------------------------------------------
__global__ void convert_all_kernel(
    const float* __restrict__ whh_c, const float* __restrict__ wih_p,
    const float* __restrict__ wih_c, const float* __restrict__ whh_p,
    const float* __restrict__ wr0,   const float* __restrict__ wr1,
    const float* __restrict__ w_in,  const float* __restrict__ w1,
    const float* __restrict__ w2,
    f16x2* __restrict__ W_M4, f16x2* __restrict__ WrT4, f16x2* __restrict__ W_P4,
    f16x2* __restrict__ W_H4, f16x2* __restrict__ W_14, f16x2* __restrict__ W_24,
    int* __restrict__ syncc)
{
  const int NA = 4*38*1800*4;
  const int NB = 4*38*600*4;
  const int NP = 4*38*1800*4;
  const int NH = 128*300*4;
  const int N1 = 318*304*4;
  const int N2 = 38*304*4;
  const int NS = 3*32*16 + 64;   // step counters (3 layers x 32 pairs) + claim pools
  const int TOT = NA+NB+NP+NH+N1+N2+NS;
  for (int idx0 = blockIdx.x*blockDim.x + threadIdx.x; idx0 < TOT; idx0 += gridDim.x*blockDim.x){
    int idx = idx0;
    if (idx < NA){
      int l    = idx/(38*1800*4);
      int rem  = idx - l*(38*1800*4);
      int kg   = rem/(1800*4);
      int rem2 = rem - kg*(1800*4);
      int o = rem2>>2, s = rem2&3;
      int c = (kg*4+s)*2;
      float v0=0.f, v1=0.f;
      if (c < 300){
        const float* src = (o<900) ? (whh_c + ((size_t)l*900+o)*300)
                                   : (wih_p + ((size_t)l*900+(o-900))*300);
        v0 = src[c]; v1 = src[c+1];
      }
      f16x2 t; t.x=(_Float16)v0; t.y=(_Float16)v1;
      W_M4[idx] = t; continue;
    }
    idx -= NA;
    if (idx < NB){
      int l    = idx/(38*600*4);
      int rem  = idx - l*(38*600*4);
      int kg   = rem/(600*4);
      int rem2 = rem - kg*(600*4);
      int t6 = rem2>>2, s = rem2&3;
      int d = t6>>1, hh = t6&1;
      int c = (kg*4+s)*2;
      float v0=0.f, v1=0.f;
      if (c < 300){
        const float* src = hh ? (wr1 + ((size_t)l*300+d)*300)
                              : (wr0 + ((size_t)l*300+d)*300);
        v0 = src[c]; v1 = src[c+1];
      }
      f16x2 t; t.x=(_Float16)v0; t.y=(_Float16)v1;
      WrT4[idx] = t; continue;
    }
    idx -= NB;
    if (idx < NP){
      int l    = idx/(38*1800*4);
      int rem  = idx - l*(38*1800*4);
      int kg   = rem/(1800*4);
      int rem2 = rem - kg*(1800*4);
      int o = rem2>>2, s = rem2&3;
      int c = (kg*4+s)*2;
      float v0=0.f, v1=0.f;
      if (c < 300){
        const float* src = (o<900) ? (wih_c + ((size_t)l*900+o)*300)
                                   : (whh_p + ((size_t)l*900+(o-900))*300);
        v0 = src[c]; v1 = src[c+1];
      }
      f16x2 t; t.x=(_Float16)v0; t.y=(_Float16)v1;
      W_P4[idx] = t; continue;
    }
    idx -= NP;
    if (idx < NH){
      int kg  = idx/(300*4);
      int rem = idx - kg*(300*4);
      int o = rem>>2, s = rem&3;
      int c = (kg*4+s)*2;
      f16x2 t; t.x=(_Float16)w_in[(size_t)o*1024+c]; t.y=(_Float16)w_in[(size_t)o*1024+c+1];
      W_H4[idx] = t; continue;
    }
    idx -= NH;
    if (idx < N1){
      int kgg = idx/(304*4);
      int rem = idx - kgg*(304*4);
      int o = rem>>2, s = rem&3;
      int segbase, seglen, kgl;
      if (kgg < 190){ int seg = kgg/38; kgl = kgg - seg*38; segbase = seg*300; seglen = 300; }
      else { int kk = kgg-190; int sf = kk>>6; kgl = kk&63; segbase = 1500 + sf*512; seglen = 512; }
      int c = (kgl*4+s)*2;
      float v0=0.f, v1=0.f;
      if (o < 300 && c < seglen){
        v0 = w1[(size_t)o*2524 + segbase + c];
        if (c+1 < seglen) v1 = w1[(size_t)o*2524 + segbase + c + 1];
      }
      f16x2 t; t.x=(_Float16)v0; t.y=(_Float16)v1;
      W_14[idx] = t; continue;
    }
    idx -= N1;
    if (idx < N2){
      int kg = idx/(304*4);
      int rem = idx - kg*(304*4);
      int o = rem>>2, s = rem&3;
      int c = (kg*4+s)*2;
      float v0=0.f, v1=0.f;
      if (o < 300 && c < 300){ v0 = w2[(size_t)o*300+c]; v1 = w2[(size_t)o*300+c+1]; }
      f16x2 t; t.x=(_Float16)v0; t.y=(_Float16)v1;
      W_24[idx] = t; continue;
    }
    idx -= N2;
    syncc[idx] = 0;
  }
}

// ---------------------------------------------------------------------------
// H0 = relu(features @ w_in^T + b_in), coalesced fp16 weights.
// ---------------------------------------------------------------------------
__global__ __launch_bounds__(256) void h0_kernel(const float* __restrict__ feat,
    const f16x2* __restrict__ WH, const float* __restrict__ b_in, float* __restrict__ H0)
{
  const int tid = threadIdx.x;
  const int r0  = blockIdx.x*8;
  __shared__ f16x2 X[8][512];
  for (int t=tid; t<8*512; t+=256){
    int r=t>>9, p=t&511, c=2*p;
    f16x2 h; h.x=(_Float16)feat[(size_t)(r0+r)*1024+c];
    h.y=(_Float16)feat[(size_t)(r0+r)*1024+c+1];
    X[r][p]=h;
  }
  __syncthreads();
  const uint4* WHu = (const uint4*)WH;
  const int o0 = tid, o1 = tid+256;
  const bool h1v = (o1 < 300);
  float acc[2][8];
  #pragma unroll
  for (int j=0;j<2;j++)
    #pragma unroll
    for (int r=0;r<8;r++) acc[j][r]=0.f;
  for (int kg=0; kg<128; kg++){
    U w0, w1;
    w0.u = WHu[(size_t)kg*300 + o0];
    if (h1v) w1.u = WHu[(size_t)kg*300 + o1];
    #pragma unroll
    for (int r=0;r<8;r++){
      const f16x2* xp = &X[r][kg*4];
      f16x2 x0=xp[0],x1=xp[1],x2=xp[2],x3=xp[3];
      acc[0][r] = fdot2a(w0.h[3],x3, fdot2a(w0.h[2],x2, fdot2a(w0.h[1],x1, fdot2a(w0.h[0],x0, acc[0][r]))));
      if (h1v)
        acc[1][r] = fdot2a(w1.h[3],x3, fdot2a(w1.h[2],x2, fdot2a(w1.h[1],x1, fdot2a(w1.h[0],x0, acc[1][r]))));
    }
  }
  {
    float bb = b_in[o0];
    #pragma unroll
    for (int r=0;r<8;r++) H0[(size_t)(r0+r)*HID + o0] = fmaxf(acc[0][r]+bb, 0.f);
  }
  if (h1v){
    float bb = b_in[o1];
    #pragma unroll
    for (int r=0;r<8;r++) H0[(size_t)(r0+r)*HID + o1] = fmaxf(acc[1][r]+bb, 0.f);
  }
}

// ---------------------------------------------------------------------------
// Fused 4-layer pipelined scan, 2 CHAINS PER WG: 128 WGs = 4 layers x 32 pairs.
// Every weight uint4 is loaded once and dotted against BOTH chains' vectors ->
// halves weight streams chip-wide, doubles arithmetic intensity. LDS ~121 KB
// naturally forces 1 WG/CU. XCC_ID-claimed layer pools (32 slots each).
// ---------------------------------------------------------------------------
__global__ __launch_bounds__(1024) void scan_pipe_kernel(
  float* __restrict__ Hball,
  const f16x2* __restrict__ W_M4, const f16x2* __restrict__ WrT4, const f16x2* __restrict__ W_P4,
  const float* __restrict__ bih_c, const float* __restrict__ bhh_c,
  const float* __restrict__ bih_p, const float* __restrict__ bhh_p,
  const float* __restrict__ gwq, const float* __restrict__ gwk, const float* __restrict__ gbv,
  const int* __restrict__ speakers, float* __restrict__ xrow, int* __restrict__ syncc)
{
  __shared__ _Float16 Hh[2][NSEQ][304];
  __shared__ float pre_s[2][1800];
  __shared__ float gates[2][1800];
  __shared__ float Mf[2][304];
  __shared__ f16x2 Mh[2][152];
  __shared__ f16x2 u01h[2][304];
  __shared__ float wgt[2][NSEQ];
  __shared__ float kd[2][NSEQ];
  __shared__ float red[2][320];
  __shared__ float xf[2][304];
  __shared__ f16x2 xh[2][152];
  __shared__ int   spk[2][NSEQ];
  __shared__ int   startA[2][NSEQ];
  __shared__ int   sLayer, sPair;

  const int tid = threadIdx.x;

  // --- claim (layer, pair) with XCD-local preference ---
  if (tid == 0){
    int xcc = 0;
    asm volatile("s_getreg_b32 %0, hwreg(HW_REG_XCC_ID)" : "=s"(xcc));
    int pref = (xcc >> 1) & 3;
    int* claimc = syncc + 3*32*16;
    int l = 0, p = 0;
    #pragma unroll 1
    for (int t=0; t<4; ++t){
      int cand = (pref + t) & 3;
      int idx = __hip_atomic_fetch_add(&claimc[cand*16], 1, __ATOMIC_RELAXED, __HIP_MEMORY_SCOPE_AGENT);
      if (idx < 32){ l = cand; p = idx; break; }
    }
    sLayer = l; sPair = p;
  }
  __syncthreads();
  const int layer = sLayer;
  const int pair  = sPair;
  const int base0 = (2*pair)*NSEQ;
  const int base1 = (2*pair+1)*NSEQ;

  const uint4* Wm4 = (const uint4*)(W_M4 + (size_t)layer*38*1800*4);
  const uint4* Wr4 = (const uint4*)(WrT4 + (size_t)layer*38*600*4);
  const uint4* Wp4 = (const uint4*)(W_P4 + (size_t)layer*38*1800*4);
  const float* HinB0 = Hball + (size_t)base0*300;
  const float* HinB1 = Hball + (size_t)base1*300;
  float* HoutB0 = Hball + ((size_t)(layer+1)*NROWS + (size_t)base0)*300;
  float* HoutB1 = Hball + ((size_t)(layer+1)*NROWS + (size_t)base1)*300;
  const float gb = gbv[layer];
  int* cntP = syncc + (layer*32 + pair)*16;
  int* cntC = (layer>0) ? (syncc + ((layer-1)*32 + pair)*16) : (int*)0;
  const float* xin  = xrow + (size_t)(((layer-1)*32 + pair)*2)*NSEQ*300;  // layer>0
  float*       xout = xrow + (size_t)((layer*32 + pair)*2)*NSEQ*300;      // layer<3

  const int w  = tid >> 6;     // wave id 0..15
  const int rc = tid >> 9;     // half 0/1 (chain for R/E phases)
  const int rt = tid & 511;

  // step-invariant per-thread regs (same for both halves)
  float bcr=0,bcz=0,bcn=0,bpr=0,bpz=0,bpn=0,wkv=0;
  if (rt < 300){
    bcr=bhh_c[layer*900+rt]; bcz=bhh_c[layer*900+300+rt]; bcn=bhh_c[layer*900+600+rt];
    bpr=bih_p[layer*900+rt]; bpz=bih_p[layer*900+300+rt]; bpn=bih_p[layer*900+600+rt];
    wkv=gwk[layer*300+rt];
  }
  float wq0r=0, wq1r=0;
  if (rt < 150){ wq0r = gwq[layer*300+2*rt]; wq1r = gwq[layer*300+2*rt+1]; }

  // P-phase mapping: waves 1..7 and 9..15 (896 threads) cover 1800 rows
  const bool isP = (tid >= 64) && (w != 8);
  const int pidx = (tid < 512) ? (tid - 64) : (tid - 128);   // 0..895 when isP
  const int po1 = pidx, po2 = 896 + pidx;
  float pb1=0, pb2=0, pb3=0;
  if (isP){
    pb1 = (po1<900) ? bih_c[layer*900+po1] : bhh_p[layer*900+po1-900];
    pb2 = (po2<900) ? bih_c[layer*900+po2] : bhh_p[layer*900+po2-900];
    if (pidx < 8) pb3 = bhh_p[layer*900+(1792+pidx)-900];
  }
  const int o1 = tid, o2 = tid+1024;
  const bool dhas2 = (o2 < 1800);

  // init
  if (tid < 64) spk[0][tid] = speakers[base0+tid];
  else if (tid < 128) spk[1][tid-64] = speakers[base1+(tid-64)];
  for (int t=tid; t<2*1800; t+=1024) ((float*)gates)[t]=0.f;
  for (int t=tid; t<2*304; t+=1024) ((float*)Mf)[t]=0.f;
  if (tid >= 128 && tid < 168){ int t=tid-128; red[t/20][300+(t%20)] = 0.f; }
  if (tid >= 168 && tid < 176){ int t=tid-168; xf[t>>2][300+(t&3)] = 0.f; }
  if (tid >= 176 && tid < 180){
    int t=tid-176; f16x2 z; z.x=(_Float16)0.f; z.y=(_Float16)0.f;
    Mh[t>>1][150+(t&1)]=z; xh[t>>1][150+(t&1)]=z;
    u01h[t>>1][150+(t&1)]=z; u01h[t>>1][302+(t&1)]=z;
  }
  __syncthreads();
  if (tid < 64){
    int s=0; for (int j=tid-1;j>=0;--j) if (spk[0][j]==spk[0][tid]){s=j;break;}
    startA[0][tid]=s;
  } else if (tid < 128){
    int t=tid-64;
    int s=0; for (int j=t-1;j>=0;--j) if (spk[1][j]==spk[1][t]){s=j;break;}
    startA[1][t]=s;
  }
  if (layer>0 && tid==0){
    while (__hip_atomic_load(cntC, __ATOMIC_RELAXED, __HIP_MEMORY_SCOPE_AGENT) < 1)
      __builtin_amdgcn_s_sleep(8);
  }
  __syncthreads();

  for (int i=0; i<NSEQ; ++i){
    // R: receive/load input row i for both chains
    if (rt < 150){
      float x0, x1;
      if (layer==0){
        const float* Hin = rc ? HinB1 : HinB0;
        float2 v = *(const float2*)(Hin + (size_t)i*300 + 2*rt);
        x0=v.x; x1=v.y;
      } else {
        const float* xi = xin + (size_t)rc*NSEQ*300 + (size_t)i*300;
        x0 = xload(xi + 2*rt);
        x1 = xload(xi + 2*rt + 1);
      }
      xf[rc][2*rt]=x0; xf[rc][2*rt+1]=x1;
      f16x2 h; h.x=(_Float16)x0; h.y=(_Float16)x1; xh[rc][rt]=h;
      red[rc][rt] = x0*wq0r + x1*wq1r;
    }
    __syncthreads();
    // P on waves 1-7,9-15 (both chains per weight load) || A: softmax on waves 0,8
    if (!isP){
      if (i > 0 && (w==0 || w==8)){
        const int c = (w==8);
        const int lane = tid & 63;
        float s = red[c][lane] + red[c][lane+64] + ((lane<22)? red[c][lane+128] : 0.f);
        #pragma unroll
        for (int o=32;o>0;o>>=1) s += __shfl_xor(s,o);
        const float q = s;
        const int st = startA[c][i];
        const bool in = (lane>=st) && (lane<i);
        float a = in ? (q + kd[c][lane] + gb) : -3.0e38f;
        float m = a;
        #pragma unroll
        for (int o=32;o>0;o>>=1) m = fmaxf(m,__shfl_xor(m,o));
        float e = in ? __expf(a-m) : 0.f;
        float ss = e;
        #pragma unroll
        for (int o=32;o>0;o>>=1) ss += __shfl_xor(ss,o);
        wgt[c][lane] = e/ss;
      }
    } else {
      float aA0=0,aA1=0,aA2=0,aA3=0, aB0=0,aB1=0,aB2=0,aB3=0;
      float eA0=0,eA1=0,eA2=0,eA3=0, eB0=0,eB1=0,eB2=0,eB3=0;
      for (int kg=0;kg<38;kg++){
        U v0, v1;
        v0.u = Wp4[(size_t)kg*1800 + po1];
        v1.u = Wp4[(size_t)kg*1800 + po2];
        f16x2 xA0=xh[0][kg*4+0],xA1=xh[0][kg*4+1],xA2=xh[0][kg*4+2],xA3=xh[0][kg*4+3];
        f16x2 xB0=xh[1][kg*4+0],xB1=xh[1][kg*4+1],xB2=xh[1][kg*4+2],xB3=xh[1][kg*4+3];
        aA0=fdot2a(v0.h[0],xA0,aA0); aA1=fdot2a(v0.h[1],xA1,aA1);
        aA2=fdot2a(v0.h[2],xA2,aA2); aA3=fdot2a(v0.h[3],xA3,aA3);
        aB0=fdot2a(v0.h[0],xB0,aB0); aB1=fdot2a(v0.h[1],xB1,aB1);
        aB2=fdot2a(v0.h[2],xB2,aB2); aB3=fdot2a(v0.h[3],xB3,aB3);
        eA0=fdot2a(v1.h[0],xA0,eA0); eA1=fdot2a(v1.h[1],xA1,eA1);
        eA2=fdot2a(v1.h[2],xA2,eA2); eA3=fdot2a(v1.h[3],xA3,eA3);
        eB0=fdot2a(v1.h[0],xB0,eB0); eB1=fdot2a(v1.h[1],xB1,eB1);
        eB2=fdot2a(v1.h[2],xB2,eB2); eB3=fdot2a(v1.h[3],xB3,eB3);
      }
      pre_s[0][po1] = (aA0+aA1)+(aA2+aA3) + pb1;
      pre_s[1][po1] = (aB0+aB1)+(aB2+aB3) + pb1;
      pre_s[0][po2] = (eA0+eA1)+(eA2+eA3) + pb2;
      pre_s[1][po2] = (eB0+eB1)+(eB2+eB3) + pb2;
      if (pidx < 8){
        const int po3 = 1792 + pidx;
        float qA0=0,qA1=0,qA2=0,qA3=0, qB0=0,qB1=0,qB2=0,qB3=0;
        for (int kg=0;kg<38;kg++){
          U v; v.u = Wp4[(size_t)kg*1800 + po3];
          f16x2 xA0=xh[0][kg*4+0],xA1=xh[0][kg*4+1],xA2=xh[0][kg*4+2],xA3=xh[0][kg*4+3];
          f16x2 xB0=xh[1][kg*4+0],xB1=xh[1][kg*4+1],xB2=xh[1][kg*4+2],xB3=xh[1][kg*4+3];
          qA0=fdot2a(v.h[0],xA0,qA0); qA1=fdot2a(v.h[1],xA1,qA1);
          qA2=fdot2a(v.h[2],xA2,qA2); qA3=fdot2a(v.h[3],xA3,qA3);
          qB0=fdot2a(v.h[0],xB0,qB0); qB1=fdot2a(v.h[1],xB1,qB1);
          qB2=fdot2a(v.h[2],xB2,qB2); qB3=fdot2a(v.h[3],xB3,qB3);
        }
        pre_s[0][po3] = (qA0+qA1)+(qA2+qA3) + pb3;
        pre_s[1][po3] = (qB0+qB1)+(qB2+qB3) + pb3;
      }
    }
    __syncthreads();
    if (i > 0){
      // B: weighted history sums, 1200 tasks (600 x 2 chains) over 1024 threads
      #pragma unroll 1
      for (int pass=0; pass<2; ++pass){
        int T = tid + pass*1024;
        if (T < 1200){
          const int c = (T >= 600);
          const int t = T - c*600;
          const int d  = (t<300)? t : (t-300);
          const int wh = (t>=300);
          const int st = startA[c][i]; const int ms = spk[c][i];
          float u=0.f;
          for (int j=st;j<i;++j){
            float sel = ((spk[c][j]==ms) != (wh!=0)) ? 1.f : 0.f;
            u += sel*wgt[c][j]*(float)Hh[c][j][d];
          }
          ((_Float16*)&u01h[c][0])[(wh?304:0) + d] = (_Float16)u;
        }
      }
      __syncthreads();
      // C: M = wr0@u0 + wr1@u1, both chains per weight load
      if (tid < 600){
        const int hh = tid&1;
        const f16x2* uA = (const f16x2*)&u01h[0][0] + hh*152;
        const f16x2* uB = (const f16x2*)&u01h[1][0] + hh*152;
        float a0=0,a1=0,a2=0,a3=0, b0=0,b1=0,b2=0,b3=0;
        for (int kg=0;kg<38;kg++){
          U v; v.u = Wr4[(size_t)kg*600 + tid];
          a0=fdot2a(v.h[0],uA[kg*4+0],a0); a1=fdot2a(v.h[1],uA[kg*4+1],a1);
          a2=fdot2a(v.h[2],uA[kg*4+2],a2); a3=fdot2a(v.h[3],uA[kg*4+3],a3);
          b0=fdot2a(v.h[0],uB[kg*4+0],b0); b1=fdot2a(v.h[1],uB[kg*4+1],b1);
          b2=fdot2a(v.h[2],uB[kg*4+2],b2); b3=fdot2a(v.h[3],uB[kg*4+3],b3);
        }
        float aA = (a0+a1)+(a2+a3);
        float aB = (b0+b1)+(b2+b3);
        float m2A = aA + __shfl_xor(aA,1);
        float m2B = aB + __shfl_xor(aB,1);
        if ((tid&1)==0){ Mf[0][tid>>1] = m2A; Mf[1][tid>>1] = m2B; }
        float moA = __shfl_xor(m2A,2);
        float moB = __shfl_xor(m2B,2);
        if ((tid&3)==0){
          f16x2 hA; hA.x=(_Float16)m2A; hA.y=(_Float16)moA; Mh[0][tid>>2]=hA;
          f16x2 hB; hB.x=(_Float16)m2B; hB.y=(_Float16)moB; Mh[1][tid>>2]=hB;
        }
      }
      __syncthreads();
      // D: gates = [whh_c ; wih_p] @ M, both chains per weight load
      {
        float aA0=0,aA1=0,aA2=0,aA3=0, aB0=0,aB1=0,aB2=0,aB3=0;
        float eA0=0,eA1=0,eA2=0,eA3=0, eB0=0,eB1=0,eB2=0,eB3=0;
        for (int kg=0;kg<38;kg++){
          U v0, v1;
          v0.u = Wm4[(size_t)kg*1800 + o1];
          if (dhas2) v1.u = Wm4[(size_t)kg*1800 + o2];
          f16x2 mA0=Mh[0][kg*4+0], mA1=Mh[0][kg*4+1], mA2=Mh[0][kg*4+2], mA3=Mh[0][kg*4+3];
          f16x2 mB0=Mh[1][kg*4+0], mB1=Mh[1][kg*4+1], mB2=Mh[1][kg*4+2], mB3=Mh[1][kg*4+3];
          aA0=fdot2a(v0.h[0],mA0,aA0); aA1=fdot2a(v0.h[1],mA1,aA1);
          aA2=fdot2a(v0.h[2],mA2,aA2); aA3=fdot2a(v0.h[3],mA3,aA3);
          aB0=fdot2a(v0.h[0],mB0,aB0); aB1=fdot2a(v0.h[1],mB1,aB1);
          aB2=fdot2a(v0.h[2],mB2,aB2); aB3=fdot2a(v0.h[3],mB3,aB3);
          if (dhas2){
            eA0=fdot2a(v1.h[0],mA0,eA0); eA1=fdot2a(v1.h[1],mA1,eA1);
            eA2=fdot2a(v1.h[2],mA2,eA2); eA3=fdot2a(v1.h[3],mA3,eA3);
            eB0=fdot2a(v1.h[0],mB0,eB0); eB1=fdot2a(v1.h[1],mB1,eB1);
            eB2=fdot2a(v1.h[2],mB2,eB2); eB3=fdot2a(v1.h[3],mB3,eB3);
          }
        }
        gates[0][o1] = (aA0+aA1)+(aA2+aA3);
        gates[1][o1] = (aB0+aB1)+(aB2+aB3);
        if (dhas2){
          gates[0][o2] = (eA0+eA1)+(eA2+eA3);
          gates[1][o2] = (eB0+eB1)+(eB2+eB3);
        }
      }
      __syncthreads();
    }
    // E: GRU combine for chain rc on thread-halves
    if (rt < 300){
      const float M = Mf[rc][rt];
      const float* ps = pre_s[rc];
      const float* gs = gates[rc];
      float r  = sigm(ps[rt] + gs[rt] + bcr);
      float z  = sigm(ps[300+rt] + gs[300+rt] + bcz);
      float n  = tanhf(ps[600+rt] + r*(gs[600+rt]+bcn));
      float C  = (1.f-z)*n + z*M;
      float rp = sigm(gs[900+rt]+bpr + ps[900+rt]);
      float zp = sigm(gs[1200+rt]+bpz + ps[1200+rt]);
      float np = tanhf(gs[1500+rt]+bpn + rp*ps[1500+rt]);
      float qv = xf[rc][rt];
      float P  = (1.f-zp)*np + zp*qv;
      float h  = C + P;
      float* Ho = rc ? HoutB1 : HoutB0;
      Ho[(size_t)i*300 + rt] = h;
      Hh[rc][i][rt] = (_Float16)h;
      red[rc][rt] = h*wkv;
      if (layer<3) xstore(xout + (size_t)rc*NSEQ*300 + (size_t)i*300 + rt, h);
    }
    asm volatile("s_waitcnt vmcnt(0)" ::: "memory");   // drain publish before counting
    __syncthreads();
    // F: kd[c][i] on waves 0 and 8; counter bump + poll on tid 0
    if (w==0 || w==8){
      const int c = (w==8);
      const int lane = tid & 63;
      float s = red[c][lane]+red[c][lane+64]+red[c][lane+128]+red[c][lane+192]+red[c][lane+256];
      #pragma unroll
      for (int o=32;o>0;o>>=1) s += __shfl_xor(s,o);
      if (lane==0) kd[c][i]=s;
    }
    if (tid==0){
      if (layer<3) __hip_atomic_fetch_add(cntP, 1, __ATOMIC_RELAXED, __HIP_MEMORY_SCOPE_AGENT);
      if (layer>0 && i<63){
        while (__hip_atomic_load(cntC, __ATOMIC_RELAXED, __HIP_MEMORY_SCOPE_AGENT) < i+2)
          __builtin_amdgcn_s_sleep(8);
      }
    }
    __syncthreads();
  }
}

// ---------------------------------------------------------------------------
// Head with fp16-dot2 GEMMs (unchanged).
// ---------------------------------------------------------------------------
__global__ __launch_bounds__(256) void head_kernel(
  const float* __restrict__ H0, const float* __restrict__ Hl1,
  const float* __restrict__ Hl2, const float* __restrict__ Hl3,
  const float* __restrict__ Hl4, const float* __restrict__ feat,
  const f16x2* __restrict__ W14, const float* __restrict__ b1,
  const f16x2* __restrict__ W24, const float* __restrict__ b2,
  const float* __restrict__ w3, const float* __restrict__ b3,
  float* __restrict__ out)
{
  const int tid = threadIdx.x;
  const int r0  = blockIdx.x*16;
  __shared__ f16x2 Xh[16*256];
  __shared__ _Float16 h1h[16*304];
  __shared__ float S2[16*304];
  const uint4* W14u = (const uint4*)W14;
  const uint4* W24u = (const uint4*)W24;

  float acc0[16], acc1[16];
  #pragma unroll
  for (int r=0;r<16;r++){ acc0[r]=0.f; acc1[r]=0.f; }
  const int o  = tid;
  const int o2 = tid + 256;
  const bool has2 = (o2 < 300);

  #pragma unroll
  for (int seg=0; seg<7; seg++){
    const float* src = (seg==0)?H0:(seg==1)?Hl1:(seg==2)?Hl2:(seg==3)?Hl3:(seg==4)?Hl4:feat;
    if (seg < 5){
      for (int t=tid; t<16*152; t+=256){
        int r=t/152, p=t-r*152, c=2*p;
        float v0 = (c<300)? src[(size_t)(r0+r)*300 + c] : 0.f;
        float v1 = (c+1<300)? src[(size_t)(r0+r)*300 + c+1] : 0.f;
        f16x2 h; h.x=(_Float16)v0; h.y=(_Float16)v1;
        Xh[r*256+p] = h;
      }
    } else {
      const int cb = (seg-5)*512;
      for (int t=tid; t<16*256; t+=256){
        int r=t>>8, p=t&255;
        float v0 = src[(size_t)(r0+r)*1024 + cb + 2*p];
        float v1 = src[(size_t)(r0+r)*1024 + cb + 2*p+1];
        f16x2 h; h.x=(_Float16)v0; h.y=(_Float16)v1;
        Xh[r*256+p] = h;
      }
    }
    __syncthreads();
    const int kgs = (seg<5)?38:64;
    const int kgo = (seg<5)? seg*38 : 190+(seg-5)*64;
    if (o < 300){
      for (int kg=0; kg<kgs; kg++){
        U a, b;
        a.u = W14u[(size_t)(kgo+kg)*304 + o];
        if (has2) b.u = W14u[(size_t)(kgo+kg)*304 + o2];
        #pragma unroll
        for (int r=0;r<16;r++){
          const f16x2* xp = &Xh[r*256 + kg*4];
          float t0 = fdot2a(a.h[0], xp[0], 0.f);
          t0 = fdot2a(a.h[1], xp[1], t0);
          t0 = fdot2a(a.h[2], xp[2], t0);
          t0 = fdot2a(a.h[3], xp[3], t0);
          acc0[r] += t0;
          if (has2){
            float t1 = fdot2a(b.h[0], xp[0], 0.f);
            t1 = fdot2a(b.h[1], xp[1], t1);
            t1 = fdot2a(b.h[2], xp[2], t1);
            t1 = fdot2a(b.h[3], xp[3], t1);
            acc1[r] += t1;
          }
        }
      }
    }
    __syncthreads();
  }
  if (o < 300){
    float bb = b1[o];
    #pragma unroll
    for (int r=0;r<16;r++) h1h[r*304+o] = (_Float16)fmaxf(acc0[r]+bb, 0.f);
  }
  if (has2){
    float bb = b1[o2];
    #pragma unroll
    for (int r=0;r<16;r++) h1h[r*304+o2] = (_Float16)fmaxf(acc1[r]+bb, 0.f);
  }
  if (tid < 4){
    #pragma unroll
    for (int r=0;r<16;r++) h1h[r*304+300+tid] = (_Float16)0.f;
  }
  __syncthreads();
  #pragma unroll
  for (int r=0;r<16;r++){ acc0[r]=0.f; acc1[r]=0.f; }
  if (o < 300){
    for (int kg=0; kg<38; kg++){
      U a, b;
      a.u = W24u[(size_t)kg*304 + o];
      if (has2) b.u = W24u[(size_t)kg*304 + o2];
      #pragma unroll
      for (int r=0;r<16;r++){
        const f16x2* xp = (const f16x2*)&h1h[r*304] + kg*4;
        float t0 = fdot2a(a.h[0], xp[0], 0.f);
        t0 = fdot2a(a.h[1], xp[1], t0);
        t0 = fdot2a(a.h[2], xp[2], t0);
        t0 = fdot2a(a.h[3], xp[3], t0);
        acc0[r] += t0;
        if (has2){
          float t1 = fdot2a(b.h[0], xp[0], 0.f);
          t1 = fdot2a(b.h[1], xp[1], t1);
          t1 = fdot2a(b.h[2], xp[2], t1);
          t1 = fdot2a(b.h[3], xp[3], t1);
          acc1[r] += t1;
        }
      }
    }
  }
  __syncthreads();
  if (o < 300){
    float bb = b2[o];
    #pragma unroll
    for (int r=0;r<16;r++) S2[r*304+o] = fmaxf(acc0[r]+bb, 0.f);
  }
  if (has2){
    float bb = b2[o2];
    #pragma unroll
    for (int r=0;r<16;r++) S2[r*304+o2] = fmaxf(acc1[r]+bb, 0.f);
  }
  __syncthreads();
  if (tid < 16*7){
    int r = tid/7, c = tid - r*7;
    float s = b3[c];
    const float* wrow = w3 + (size_t)c*HID;
    for (int k=0;k<300;k++) s += wrow[k]*S2[r*304+k];
    out[(size_t)(r0+r)*7 + c] = s;
  }
}

// ---------------------------------------------------------------------------
extern "C" void kernel_launch(void* const* d_in, const int* in_sizes, int n_in,
                              void* d_out, int out_size, void* d_ws, size_t ws_size,
                              hipStream_t stream)
{
  (void)in_sizes; (void)n_in; (void)out_size; (void)ws_size;
  const float* feat  = (const float*)d_in[0];
  const int*   spk   = (const int*)d_in[1];
  const float* w_in  = (const float*)d_in[2];
  const float* b_in  = (const float*)d_in[3];
  const float* gwq   = (const float*)d_in[4];
  const float* gwk   = (const float*)d_in[5];
  const float* gb    = (const float*)d_in[6];
  const float* wr0   = (const float*)d_in[7];
  const float* wr1   = (const float*)d_in[8];
  const float* wih_c = (const float*)d_in[9];
  const float* whh_c = (const float*)d_in[10];
  const float* bih_c = (const float*)d_in[11];
  const float* bhh_c = (const float*)d_in[12];
  const float* wih_p = (const float*)d_in[13];
  const float* whh_p = (const float*)d_in[14];
  const float* bih_p = (const float*)d_in[15];
  const float* bhh_p = (const float*)d_in[16];
  const float* w1    = (const float*)d_in[17];
  const float* b1    = (const float*)d_in[18];
  const float* w2    = (const float*)d_in[19];
  const float* b2    = (const float*)d_in[20];
  const float* w3    = (const float*)d_in[21];
  const float* b3    = (const float*)d_in[22];
  float* out = (float*)d_out;

  char* ws = (char*)d_ws;
  size_t off = 0;
  auto alloc = [&](size_t bytes)->void*{
    void* p = ws + off;
    off += (bytes + 255) & ~(size_t)255;
    return p;
  };
  f16x2* W_M4 = (f16x2*)alloc((size_t)4*38*1800*4 * sizeof(f16x2));
  f16x2* WrT4 = (f16x2*)alloc((size_t)4*38*600*4  * sizeof(f16x2));
  f16x2* W_P4 = (f16x2*)alloc((size_t)4*38*1800*4 * sizeof(f16x2));
  f16x2* W_H4 = (f16x2*)alloc((size_t)128*300*4   * sizeof(f16x2));
  f16x2* W_14 = (f16x2*)alloc((size_t)318*304*4   * sizeof(f16x2));
  f16x2* W_24 = (f16x2*)alloc((size_t)38*304*4    * sizeof(f16x2));
  float* Hball = (float*)alloc((size_t)5*NROWS*HID*sizeof(float));
  float* xrow  = (float*)alloc((size_t)3*64*NSEQ*HID*sizeof(float));
  int*   syncc = (int*)alloc((size_t)(3*32*16 + 64)*sizeof(int));

  {
    const int tot = 4*38*1800*4 + 4*38*600*4 + 4*38*1800*4 + 128*300*4
                  + 318*304*4 + 38*304*4 + (3*32*16 + 64);
    convert_all_kernel<<<(tot+255)/256, 256, 0, stream>>>(whh_c, wih_p, wih_c, whh_p,
        wr0, wr1, w_in, w1, w2, W_M4, WrT4, W_P4, W_H4, W_14, W_24, syncc);
  }
  h0_kernel<<<NROWS/8, 256, 0, stream>>>(feat, W_H4, b_in, Hball);

  scan_pipe_kernel<<<128, 1024, 0, stream>>>(Hball, W_M4, WrT4, W_P4,
      bih_c, bhh_c, bih_p, bhh_p, gwq, gwk, gb, spk, xrow, syncc);

  head_kernel<<<NROWS/16, 256, 0, stream>>>(
      Hball, Hball + (size_t)NROWS*HID, Hball + (size_t)2*NROWS*HID,
      Hball + (size_t)3*NROWS*HID, Hball + (size_t)4*NROWS*HID,
      feat, W_14, b1, W_24, b2, w3, b3, out);
}